// Round 7
// baseline (201.101 us; speedup 1.0000x reference)
//
#include <hip/hip_runtime.h>
#include <cmath>

// ---------------------------------------------------------------------------
// GAT layer: N=100000 nodes, IN=128, OUT=32, H=4 (H*OUT=128), E=1.6M edges.
// Pipeline:
//   K1  k_gemm   : xw = x@W [N,128] packed bf16 (one 128x128 tile per block),
//                  fused a_src/a_dst logits [N,4] pre-scaled by log2(e)
//   CSR build (two-level bucketed, LDS-atomic only):
//     p1_hist    : per-block LDS histogram over NB dst-buckets
//     p2a_bsum   : bucket totals
//     p2b_bscan  : exclusive scan of bucket totals -> bucket bases
//     p2c_brow   : per-bucket scan across blocks -> absolute block cursors
//     p3_part    : scatter packed (dloc<<24|src) into bucket segments
//     p4_local   : per-bucket: degree hist + scan -> offs; scatter srcs AND
//                  compute per-edge softmax numerators palpha[e][4] (exp2 form)
//   K3  k_agg    : wave per node, 2 edges in flight per wave (half-wave each,
//                  4 ch/lane via 8B bf16x4 gather); sum p, p*x; ELU; row write
// ---------------------------------------------------------------------------

#define LOG2E 1.44269504088896340736f

typedef float f32x2 __attribute__((ext_vector_type(2)));
typedef float f32x4 __attribute__((ext_vector_type(4)));

__device__ __forceinline__ float fast_exp2(float x) {
#if __has_builtin(__builtin_amdgcn_exp2f)
  return __builtin_amdgcn_exp2f(x);
#else
  return exp2f(x);
#endif
}

__device__ __forceinline__ unsigned bf16_rne(float f) {
  unsigned u = __float_as_uint(f);
  return (u + 0x7fffu + ((u >> 16) & 1u)) >> 16;
}
__device__ __forceinline__ float bf_lo(unsigned v) {
  return __uint_as_float(v << 16);
}
__device__ __forceinline__ float bf_hi(unsigned v) {
  return __uint_as_float(v & 0xffff0000u);
}

// inclusive block scan; lds must hold >= blockDim/64 ints
__device__ __forceinline__ int blockInclScan(int v, int tid, int* lds) {
  int lane = tid & 63;
  int wid = tid >> 6;
#pragma unroll
  for (int off = 1; off < 64; off <<= 1) {
    int t = __shfl_up(v, off);
    if (lane >= off) v += t;
  }
  if (lane == 63) lds[wid] = v;
  __syncthreads();
  int add = 0;
  for (int i = 0; i < wid; ++i) add += lds[i];
  v += add;
  __syncthreads();
  return v;
}

// ---------------- K1: GEMM + attention logits ----------------
// grid ceil(N/128), block 256.  tx = tid&15 (16 col-groups of 8 = 128 cols),
// ty = tid>>4 (16 row-groups of 8 = 128 rows).  k-chunked by 32.
__global__ __launch_bounds__(256) void k_gemm(
    const float* __restrict__ x, const float* __restrict__ Wm,
    const float* __restrict__ att_src, const float* __restrict__ att_dst,
    unsigned* __restrict__ xwb, float* __restrict__ a_src,
    float* __restrict__ a_dst, int N) {
  __shared__ float xs_t[32][132];  // k-major x tile
  __shared__ float Wl[32][128];
  const int tid = threadIdx.x;
  const int tx = tid & 15;
  const int ty = tid >> 4;
  const int row0 = blockIdx.x * 128;

  float acc[8][8];
#pragma unroll
  for (int r = 0; r < 8; ++r)
#pragma unroll
    for (int c = 0; c < 8; ++c) acc[r][c] = 0.f;

  for (int kc = 0; kc < 4; ++kc) {
    __syncthreads();
    // stage x chunk: 128 rows x 32 k = 1024 float4, 4 per thread
#pragma unroll
    for (int j = 0; j < 4; ++j) {
      int f = tid + j * 256;
      int r = f >> 3, k4 = f & 7;
      int row = row0 + r;
      float4 v = make_float4(0.f, 0.f, 0.f, 0.f);
      if (row < N) v = *(const float4*)&x[(size_t)row * 128 + kc * 32 + k4 * 4];
      xs_t[k4 * 4 + 0][r] = v.x;
      xs_t[k4 * 4 + 1][r] = v.y;
      xs_t[k4 * 4 + 2][r] = v.z;
      xs_t[k4 * 4 + 3][r] = v.w;
    }
    // stage W chunk: 32 k x 128 cols = 1024 float4, 4 per thread
#pragma unroll
    for (int j = 0; j < 4; ++j) {
      int f = tid + j * 256;
      int kr = f >> 5, c4 = f & 31;
      *(float4*)&Wl[kr][c4 * 4] =
          *(const float4*)&Wm[(size_t)(kc * 32 + kr) * 128 + c4 * 4];
    }
    __syncthreads();
#pragma unroll 4
    for (int k = 0; k < 32; ++k) {
      float wv[8], xv[8];
      *(float4*)&wv[0] = *(const float4*)&Wl[k][tx * 8];
      *(float4*)&wv[4] = *(const float4*)&Wl[k][tx * 8 + 4];
      *(float4*)&xv[0] = *(const float4*)&xs_t[k][ty * 8];
      *(float4*)&xv[4] = *(const float4*)&xs_t[k][ty * 8 + 4];
#pragma unroll
      for (int r = 0; r < 8; ++r)
#pragma unroll
        for (int c = 0; c < 8; ++c) acc[r][c] = fmaf(xv[r], wv[c], acc[r][c]);
    }
  }

  float att_s[8], att_d[8];
#pragma unroll
  for (int c = 0; c < 8; ++c) {
    att_s[c] = att_src[tx * 8 + c];
    att_d[c] = att_dst[tx * 8 + c];
  }

#pragma unroll
  for (int r = 0; r < 8; ++r) {
    int row = row0 + ty * 8 + r;
    bool ok = row < N;
    float vs = 0.f, vd = 0.f;
#pragma unroll
    for (int c = 0; c < 8; ++c) {
      vs += acc[r][c] * att_s[c];
      vd += acc[r][c] * att_d[c];
    }
    // reduce across the 4 tx-lanes (32 cols) of each head
    vs += __shfl_xor(vs, 1);
    vs += __shfl_xor(vs, 2);
    vd += __shfl_xor(vd, 1);
    vd += __shfl_xor(vd, 2);
    if (ok) {
      uint4 pk;
      pk.x = bf16_rne(acc[r][0]) | (bf16_rne(acc[r][1]) << 16);
      pk.y = bf16_rne(acc[r][2]) | (bf16_rne(acc[r][3]) << 16);
      pk.z = bf16_rne(acc[r][4]) | (bf16_rne(acc[r][5]) << 16);
      pk.w = bf16_rne(acc[r][6]) | (bf16_rne(acc[r][7]) << 16);
      *(uint4*)&xwb[(size_t)row * 64 + tx * 4] = pk;
      if ((tx & 3) == 0) {
        a_src[row * 4 + (tx >> 2)] = vs * LOG2E;
        a_dst[row * 4 + (tx >> 2)] = vd * LOG2E;
      }
    }
  }
}

// ---------------- bucketed CSR build ----------------
#define CHUNK 4096

// P1: per-block histogram over buckets -> bh[b*NBLK + blk]
__global__ __launch_bounds__(256) void p1_hist(const int* __restrict__ ei, int E,
                                               int EL, int NB, int NBLK,
                                               int* __restrict__ bh) {
  __shared__ int lh[512];
  int tid = threadIdx.x;
  lh[tid] = 0;
  lh[tid + 256] = 0;
  __syncthreads();
  int base_e = blockIdx.x * CHUNK;
#pragma unroll
  for (int j = 0; j < CHUNK / 256; ++j) {
    int e = base_e + j * 256 + tid;
    if (e < EL) {
      int dst = (e < E) ? ei[E + e] : (e - E);
      atomicAdd(&lh[dst >> 8], 1);
    }
  }
  __syncthreads();
  for (int b = tid; b < NB; b += 256) bh[(size_t)b * NBLK + blockIdx.x] = lh[b];
}

// P2a: bucket totals
__global__ __launch_bounds__(256) void p2a_bsum(const int* __restrict__ bh,
                                                int* __restrict__ btot, int NBLK) {
  __shared__ int red[256];
  int b = blockIdx.x;
  int s = 0;
  for (int j = threadIdx.x; j < NBLK; j += 256) s += bh[(size_t)b * NBLK + j];
  red[threadIdx.x] = s;
  __syncthreads();
  for (int st = 128; st > 0; st >>= 1) {
    if (threadIdx.x < st) red[threadIdx.x] += red[threadIdx.x + st];
    __syncthreads();
  }
  if (threadIdx.x == 0) btot[b] = red[0];
}

// P2b: exclusive scan of bucket totals -> bbase  (single block, 512 threads)
__global__ __launch_bounds__(512) void p2b_bscan(const int* __restrict__ btot,
                                                 int* __restrict__ bbase, int NB) {
  __shared__ int lds[8];
  int i = threadIdx.x;
  int v = (i < NB) ? btot[i] : 0;
  int incl = blockInclScan(v, i, lds);
  if (i < NB) bbase[i] = incl - v;
}

// P2c: per-bucket exclusive scan across blocks (row of bh), + bbase (NBLK<=512)
__global__ __launch_bounds__(256) void p2c_brow(int* __restrict__ bh,
                                                const int* __restrict__ bbase,
                                                int NBLK) {
  __shared__ int lds[4];
  __shared__ int ctot;
  int b = blockIdx.x;
  int tid = threadIdx.x;
  int base = bbase[b];
  int v0 = (tid < NBLK) ? bh[(size_t)b * NBLK + tid] : 0;
  int incl0 = blockInclScan(v0, tid, lds);
  if (tid < NBLK) bh[(size_t)b * NBLK + tid] = base + incl0 - v0;
  if (tid == 255) ctot = incl0;
  __syncthreads();
  int base1 = base + ctot;
  int j = 256 + tid;
  int v1 = (j < NBLK) ? bh[(size_t)b * NBLK + j] : 0;
  int incl1 = blockInclScan(v1, tid, lds);
  if (j < NBLK) bh[(size_t)b * NBLK + j] = base1 + incl1 - v1;
}

// P3: partition edges into bucket segments, packed word (dloc<<24 | src)
__global__ __launch_bounds__(256) void p3_part(const int* __restrict__ ei, int E,
                                               int EL, int NB, int NBLK,
                                               const int* __restrict__ bh,
                                               unsigned* __restrict__ tmp) {
  __shared__ int lc[512];
  int tid = threadIdx.x;
  for (int b = tid; b < NB; b += 256) lc[b] = bh[(size_t)b * NBLK + blockIdx.x];
  __syncthreads();
  int base_e = blockIdx.x * CHUNK;
#pragma unroll
  for (int j = 0; j < CHUNK / 256; ++j) {
    int e = base_e + j * 256 + tid;
    if (e < EL) {
      int src, dst;
      if (e < E) {
        src = ei[e];
        dst = ei[E + e];
      } else {
        src = e - E;
        dst = e - E;
      }
      int pos = atomicAdd(&lc[dst >> 8], 1);
      tmp[pos] = ((unsigned)(dst & 255) << 24) | (unsigned)src;
    }
  }
}

// P4: per-bucket local CSR (512 threads): LDS degree hist + scan -> offs;
// scatter srcs AND compute per-edge softmax numerators palpha[pos] (f32x4,
// exp2 form; logits already scaled by log2e).
__global__ __launch_bounds__(512) void p4_local(const unsigned* __restrict__ tmp,
                                                const int* __restrict__ bbase,
                                                const int* __restrict__ btot,
                                                const float* __restrict__ asrc,
                                                const float* __restrict__ adst,
                                                int N, int NB, int EL,
                                                int* __restrict__ offs,
                                                int* __restrict__ srcs,
                                                f32x4* __restrict__ palpha) {
  __shared__ int deg[256];
  __shared__ int cur[256];
  __shared__ f32x4 ads[256];
  __shared__ int lds[8];
  int b = blockIdx.x;
  int tid = threadIdx.x;
  int beg = bbase[b];
  int end = beg + btot[b];
  if (tid < 256) {
    deg[tid] = 0;
    int idx = b * 256 + tid;
    f32x4 z = {0.f, 0.f, 0.f, 0.f};
    ads[tid] = (idx < N) ? *(const f32x4*)&adst[idx * 4] : z;
  }
  __syncthreads();
  for (int k = beg + tid; k < end; k += 512) {
    unsigned w = tmp[k];
    atomicAdd(&deg[w >> 24], 1);
  }
  __syncthreads();
  int v = (tid < 256) ? deg[tid] : 0;
  int incl = blockInclScan(v, tid, lds);
  if (tid < 256) {
    int excl = incl - v;
    int idx = b * 256 + tid;
    if (idx < N) offs[idx] = beg + excl;
    cur[tid] = beg + excl;
  }
  if (b == NB - 1 && tid == 0) offs[N] = EL;
  __syncthreads();
  for (int k = beg + tid; k < end; k += 512) {
    unsigned w = tmp[k];
    int dloc = w >> 24;
    int src = (int)(w & 0xFFFFFFu);
    int pos = atomicAdd(&cur[dloc], 1);
    srcs[pos] = src;
    f32x4 as = *(const f32x4*)&asrc[src * 4];
    f32x4 ad = ads[dloc];
    f32x4 p;
    float t0 = as.x + ad.x, t1 = as.y + ad.y, t2 = as.z + ad.z, t3 = as.w + ad.w;
    p.x = fast_exp2(fmaxf(t0, 0.2f * t0));
    p.y = fast_exp2(fmaxf(t1, 0.2f * t1));
    p.z = fast_exp2(fmaxf(t2, 0.2f * t2));
    p.w = fast_exp2(fmaxf(t3, 0.2f * t3));
    palpha[pos] = p;
  }
}

// ---------------- K3: per-node aggregate ----------------
// wave per node; half-wave 0 = even edges, half-wave 1 = odd edges.
// lane covers 4 channels (uint2 = 4 bf16).  Unroll 2 per half (4 edges/wave
// in flight).  Halves combined via shfl_xor(32) at the end.
__global__ __launch_bounds__(256) void k_agg(
    const int* __restrict__ srcs, const int* __restrict__ offs,
    const unsigned* __restrict__ xwb, const float* __restrict__ palpha,
    const float* __restrict__ bias, float* __restrict__ out, int N) {
  int gw = (int)(((size_t)blockIdx.x * blockDim.x + threadIdx.x) >> 6);
  int lane = threadIdx.x & 63;
  if (gw >= N) return;
  int beg = offs[gw];
  int end = offs[gw + 1];
  int half = lane >> 5;
  int l5 = lane & 31;
  int h = l5 >> 3;  // head of this lane's 4 channels
  const unsigned* xr = xwb + l5 * 2;

  float sA = 0.f, sB = 0.f;
  float a0 = 0.f, a1 = 0.f, a2 = 0.f, a3 = 0.f;
  float b0 = 0.f, b1 = 0.f, b2 = 0.f, b3 = 0.f;
  int i = beg + half;
  for (; i + 2 < end; i += 4) {
    int eA = srcs[i];
    int eB = srcs[i + 2];
    float pA = palpha[(size_t)i * 4 + h];
    float pB = palpha[(size_t)(i + 2) * 4 + h];
    uint2 vA = *(const uint2*)(xr + (size_t)eA * 64);
    uint2 vB = *(const uint2*)(xr + (size_t)eB * 64);
    sA += pA;
    sB += pB;
    a0 = fmaf(pA, bf_lo(vA.x), a0);
    a1 = fmaf(pA, bf_hi(vA.x), a1);
    a2 = fmaf(pA, bf_lo(vA.y), a2);
    a3 = fmaf(pA, bf_hi(vA.y), a3);
    b0 = fmaf(pB, bf_lo(vB.x), b0);
    b1 = fmaf(pB, bf_hi(vB.x), b1);
    b2 = fmaf(pB, bf_lo(vB.y), b2);
    b3 = fmaf(pB, bf_hi(vB.y), b3);
  }
  if (i < end) {
    int eA = srcs[i];
    float pA = palpha[(size_t)i * 4 + h];
    uint2 vA = *(const uint2*)(xr + (size_t)eA * 64);
    sA += pA;
    a0 = fmaf(pA, bf_lo(vA.x), a0);
    a1 = fmaf(pA, bf_hi(vA.x), a1);
    a2 = fmaf(pA, bf_lo(vA.y), a2);
    a3 = fmaf(pA, bf_hi(vA.y), a3);
  }
  float s = sA + sB;
  a0 += b0;
  a1 += b1;
  a2 += b2;
  a3 += b3;
  // combine the two halves (even/odd edge partial sums)
  s += __shfl_xor(s, 32);
  a0 += __shfl_xor(a0, 32);
  a1 += __shfl_xor(a1, 32);
  a2 += __shfl_xor(a2, 32);
  a3 += __shfl_xor(a3, 32);

  if (half == 0) {
    float inv = 1.f / s;
    float4 bv = *(const float4*)&bias[l5 * 4];
    float o0 = fmaf(a0, inv, bv.x);
    float o1 = fmaf(a1, inv, bv.y);
    float o2 = fmaf(a2, inv, bv.z);
    float o3 = fmaf(a3, inv, bv.w);
    o0 = o0 > 0.f ? o0 : fast_exp2(o0 * LOG2E) - 1.f;  // ELU
    o1 = o1 > 0.f ? o1 : fast_exp2(o1 * LOG2E) - 1.f;
    o2 = o2 > 0.f ? o2 : fast_exp2(o2 * LOG2E) - 1.f;
    o3 = o3 > 0.f ? o3 : fast_exp2(o3 * LOG2E) - 1.f;
    f32x4 o = {o0, o1, o2, o3};
    __builtin_nontemporal_store(o, (f32x4*)&out[(size_t)gw * 128 + l5 * 4]);
  }
}

// ---------------------------------------------------------------------------
extern "C" void kernel_launch(void* const* d_in, const int* in_sizes, int n_in,
                              void* d_out, int out_size, void* d_ws, size_t ws_size,
                              hipStream_t stream) {
  const float* x = (const float*)d_in[0];
  const int* ei = (const int*)d_in[1];
  const float* Wm = (const float*)d_in[2];
  const float* att_src = (const float*)d_in[3];
  const float* att_dst = (const float*)d_in[4];
  const float* bias = (const float*)d_in[5];
  float* out = (float*)d_out;

  const int N = in_sizes[0] / 128;
  const int E = in_sizes[1] / 2;
  const int EL = E + N;
  const int NB = (N + 255) >> 8;
  const int NBLK = (EL + CHUNK - 1) / CHUNK;

  size_t off = 0;
  auto carve = [&](size_t bytes) -> void* {
    void* p = (char*)d_ws + off;
    off += (bytes + 255) & ~(size_t)255;
    return p;
  };
  unsigned* xwb = (unsigned*)carve((size_t)N * 64 * 4);  // bf16-packed [N][64]
  float* a_src = (float*)carve((size_t)N * 4 * 4);
  float* a_dst = (float*)carve((size_t)N * 4 * 4);
  int* offs = (int*)carve((size_t)(N + 1) * 4);
  int* srcs = (int*)carve((size_t)EL * 4);
  unsigned* tmp = (unsigned*)carve((size_t)EL * 4);
  f32x4* palpha = (f32x4*)carve((size_t)EL * 16);
  int* bh = (int*)carve((size_t)NB * NBLK * 4);
  int* btot = (int*)carve((size_t)NB * 4);
  int* bbase = (int*)carve((size_t)NB * 4);

  k_gemm<<<(N + 127) / 128, 256, 0, stream>>>(x, Wm, att_src, att_dst, xwb,
                                              a_src, a_dst, N);

  p1_hist<<<NBLK, 256, 0, stream>>>(ei, E, EL, NB, NBLK, bh);
  p2a_bsum<<<NB, 256, 0, stream>>>(bh, btot, NBLK);
  p2b_bscan<<<1, 512, 0, stream>>>(btot, bbase, NB);
  p2c_brow<<<NB, 256, 0, stream>>>(bh, bbase, NBLK);
  p3_part<<<NBLK, 256, 0, stream>>>(ei, E, EL, NB, NBLK, bh, tmp);
  p4_local<<<NB, 512, 0, stream>>>(tmp, bbase, btot, a_src, a_dst, N, NB, EL,
                                   offs, srcs, palpha);

  int abl = (int)(((size_t)N * 64 + 255) / 256);
  k_agg<<<abl, 256, 0, stream>>>(srcs, offs, xwb, (const float*)palpha, bias,
                                 out, N);
}